// Round 18
// baseline (58.992 us; speedup 1.0000x reference)
//
#include <hip/hip_runtime.h>
#include <hip/hip_bf16.h>
#include <hip/hip_fp16.h>

// HeadUpdator: fused bilinear-upsample+sigmoid+einsum (MFMA) + per-row gating MLP.
// feat (8,64,256,256) f32, head (8,80,64,1) f32, pred (8,80,128,128) f32
// -> out (8,80,64,1,1) f32.
// Round-18: BYTE ECONOMY v2. 4 output rows per block (rows 4q..4q+3 share
// pred rowsets 2q-1..2q+2: 4 rowsets for 4 rows vs 6 for two pairs) and ONE
// acc -> ONE partial slot per block (npart 128, partial traffic halved again).
// Movement 302 -> 239 MB. Lerp schedule: row0 .25U+.75V / reload U / row1
// .25U+.75V / row2 .25V+.75U / reload V / row3 .25V+.75U.

using bf16x8 = __attribute__((ext_vector_type(8))) short;
using f32x4  = __attribute__((ext_vector_type(4))) float;

__device__ __forceinline__ unsigned pk2(float lo, float hi) {
  union { __hip_bfloat162 h2; unsigned u; } cv;
  cv.h2 = __float22bfloat162_rn(make_float2(lo, hi));
  return cv.u;
}
// sigmoid(0.25a + 0.75b), -log2e folded into the lerp weights
__device__ __forceinline__ float sigAB(float a, float b) {
  return __builtin_amdgcn_rcpf(1.0f + __builtin_amdgcn_exp2f(-0.36067376f * a - 1.08202128f * b));
}
// sigmoid(0.75a + 0.25b)
__device__ __forceinline__ float sigBA(float a, float b) {
  return __builtin_amdgcn_rcpf(1.0f + __builtin_amdgcn_exp2f(-1.08202128f * a - 0.36067376f * b));
}

// Produce one upsampled sigmoid row into Pfrag: y = 0.25*pL + 0.75*pH.
// Thread map: gg = tid&15 (4-col groups), nbp = tid>>4 (class base).
// Slot bijection (r8 family, measured 0 conflicts).
__device__ __forceinline__ void produce_row(
    const float4 (&pL)[5], const float4 (&pH)[5],
    const float (&sL)[5], const float (&sH)[5],
    int half, int gg, int nbp, unsigned short* __restrict__ Pfrag) {
  #pragma unroll
  for (int i = 0; i < 5; ++i) {
    const float sc = 0.25f * sL[i] + 0.75f * sH[i];
    const float y0 = 0.25f * pL[i].x + 0.75f * pH[i].x;
    const float y1 = 0.25f * pL[i].y + 0.75f * pH[i].y;
    const float y2 = 0.25f * pL[i].z + 0.75f * pH[i].z;
    const float y3 = 0.25f * pL[i].w + 0.75f * pH[i].w;
    float yl = __shfl_up(y3, 1, 16);
    float yr = __shfl_down(y0, 1, 16);
    if (gg == 0)  yl = half ? sc : y0;   // left edge: scalar col 63 / clamp
    if (gg == 15) yr = half ? y3 : sc;   // right edge: clamp / scalar col 64
    float P[8];
    P[0] = sigAB(yl, y0); P[1] = sigBA(y0, y1);
    P[2] = sigAB(y0, y1); P[3] = sigBA(y1, y2);
    P[4] = sigAB(y1, y2); P[5] = sigBA(y2, y3);
    P[6] = sigAB(y2, y3); P[7] = sigBA(y3, yr);
    uint4 s;
    s.x = pk2(P[0], P[1]); s.y = pk2(P[2], P[3]);
    s.z = pk2(P[4], P[5]); s.w = pk2(P[6], P[7]);
    const int ks = gg >> 2, kgw = gg & 3;
    const int slot = kgw * 16 + ((nbp ^ ks ^ (kgw << 1)) & 15);
    *(uint4*)&Pfrag[(((ks * 5 + i) * 64) + slot) * 8] = s;
  }
}

// MFMA one feat row-half against Pfrag (r13's proven inline-feat shape).
__device__ __forceinline__ void mfma_row(
    const float* __restrict__ fb, const unsigned short* __restrict__ Pfrag,
    int ch16, int kg, f32x4 (&acc)[5]) {
  #pragma unroll
  for (int ks = 0; ks < 4; ++ks) {
    const int pw = ks * 32 + kg * 8;
    const float4 f0 = *(const float4*)(fb + pw);
    const float4 f1 = *(const float4*)(fb + pw + 4);
    union { uint4 u; bf16x8 v; } bu;
    bu.u.x = pk2(f0.x, f0.y); bu.u.y = pk2(f0.z, f0.w);
    bu.u.z = pk2(f1.x, f1.y); bu.u.w = pk2(f1.z, f1.w);
    const int slot = kg * 16 + ((ch16 ^ ks ^ (kg << 1)) & 15);
    #pragma unroll
    for (int m = 0; m < 5; ++m) {
      const bf16x8 af = *(const bf16x8*)&Pfrag[(((ks * 5 + m) * 64) + slot) * 8];
      acc[m] = __builtin_amdgcn_mfma_f32_16x16x32_bf16(af, bu.v, acc[m], 0, 0, 0);
    }
  }
}

// ---------------- Kernel 1: 4-row half assemble ----------------
// grid = 1024 (8 b x 64 q x 2 half), 256 threads, LDS 20 KB.
__global__ __launch_bounds__(256, 4) void k_assemble_quad(
    const float* __restrict__ feat, const float* __restrict__ pred,
    __half* __restrict__ partial) {
  __shared__ __align__(16) unsigned short Pfrag[20 * 64 * 8];  // 20 KB

  // XCD-chunked bijective swizzle (nwg=1024, 128 per XCD).
  const int bid = blockIdx.x;
  const int wg  = (bid & 7) * 128 + (bid >> 3);
  const int half = wg & 1;
  const int q    = (wg >> 1) & 63;
  const int b    = wg >> 7;

  const int tid = threadIdx.x;
  const int gg = tid & 15, nbp = tid >> 4;           // pred-phase coords
  const int wid = tid >> 6, l = tid & 63;            // mfma-phase coords
  const int ch16 = l & 15, kg = l >> 4, c0 = wid << 4;

  const int rA = (q > 0) ? 2 * q - 1 : 0;
  const int rB = 2 * q;
  const int rC = 2 * q + 1;
  const int rD = (q < 63) ? 2 * q + 2 : 127;

  const int cbase = half << 6;          // 0 or 64 (16B aligned)
  const int csc   = 64 - half;          // halo col: 64 (half0) / 63 (half1)
  const float* pbat  = pred + (((size_t)(b * 80)) << 14);
  const float* fbase = feat + (((size_t)(b * 64 + c0 + ch16)) << 16) + (half << 7);
  const int h0 = 4 * q;

  f32x4 acc[5] = {};
  float4 pU[5], pV[5];
  float sU[5], sV[5];

  // Load U<-rA, V<-rB.
  #pragma unroll
  for (int i = 0; i < 5; ++i) {
    const float* pb = pbat + (((size_t)(nbp + 16 * i)) << 14);
    pU[i] = *(const float4*)(pb + (rA << 7) + cbase + 4 * gg);
    pV[i] = *(const float4*)(pb + (rB << 7) + cbase + 4 * gg);
    sU[i] = pb[(rA << 7) + csc];
    sV[i] = pb[(rB << 7) + csc];
  }

  // ---- row0 (h0): .25U+.75V ----
  produce_row(pU, pV, sU, sV, half, gg, nbp, Pfrag);
  __syncthreads();
  // reload U <- rC (rides under MFMA row0)
  #pragma unroll
  for (int i = 0; i < 5; ++i) {
    const float* pb = pbat + (((size_t)(nbp + 16 * i)) << 14);
    pU[i] = *(const float4*)(pb + (rC << 7) + cbase + 4 * gg);
    sU[i] = pb[(rC << 7) + csc];
  }
  mfma_row(fbase + (size_t)(h0 + 0) * 256, Pfrag, ch16, kg, acc);
  __syncthreads();

  // ---- row1 (h0+1): .25U+.75V  (U=rC, V=rB) ----
  produce_row(pU, pV, sU, sV, half, gg, nbp, Pfrag);
  __syncthreads();
  mfma_row(fbase + (size_t)(h0 + 1) * 256, Pfrag, ch16, kg, acc);
  __syncthreads();

  // ---- row2 (h0+2): .25V+.75U  (V=rB, U=rC) ----
  produce_row(pV, pU, sV, sU, half, gg, nbp, Pfrag);
  __syncthreads();
  // reload V <- rD (rides under MFMA row2)
  #pragma unroll
  for (int i = 0; i < 5; ++i) {
    const float* pb = pbat + (((size_t)(nbp + 16 * i)) << 14);
    pV[i] = *(const float4*)(pb + (rD << 7) + cbase + 4 * gg);
    sV[i] = pb[(rD << 7) + csc];
  }
  mfma_row(fbase + (size_t)(h0 + 2) * 256, Pfrag, ch16, kg, acc);
  __syncthreads();

  // ---- row3 (h0+3): .25V+.75U  (V=rD, U=rC) ----
  produce_row(pV, pU, sV, sU, half, gg, nbp, Pfrag);
  __syncthreads();
  mfma_row(fbase + (size_t)(h0 + 3) * 256, Pfrag, ch16, kg, acc);

  // D frag: col = lane&15 (channel), row = (lane>>4)*4 + q_idx (class).
  __half* po = partial + ((size_t)(b * 128 + q * 2 + half)) * (80 * 64);
  #pragma unroll
  for (int m = 0; m < 5; ++m) {
    #pragma unroll
    for (int qq = 0; qq < 4; ++qq) {
      const int n = m * 16 + kg * 4 + qq;
      po[n * 64 + c0 + ch16] = __float2half(acc[m][qq]);
    }
  }
}

// ---------------- Kernel 2: reduce + head-update chain ----------------
__device__ __forceinline__ float wred64(float v) {
  #pragma unroll
  for (int off = 32; off > 0; off >>= 1) v += __shfl_xor(v, off, 64);
  return v;
}
__device__ __forceinline__ float lnorm(float x, const float* __restrict__ g,
                                       const float* __restrict__ be, int l) {
  const float m = wred64(x) * 0.015625f;
  const float d = x - m;
  const float var = wred64(d * d) * 0.015625f;
  return d * rsqrtf(var + 1e-5f) * g[l] + be[l];
}
__device__ __forceinline__ float sigmf(float x) {
  return __builtin_amdgcn_rcpf(1.0f + __builtin_amdgcn_exp2f(-1.44269504f * x));
}

// grid = 640 blocks (one per output row), 256 threads.
__global__ __launch_bounds__(256) void k_head(
    const __half* __restrict__ partial, const float* __restrict__ head,
    const float* __restrict__ Wpt, const float* __restrict__ bpt,
    const float* __restrict__ Wht, const float* __restrict__ bht,
    const float* __restrict__ Wpg, const float* __restrict__ bpg,
    const float* __restrict__ Whg, const float* __restrict__ bhg,
    const float* __restrict__ Wfc, const float* __restrict__ bfc,
    const float* __restrict__ g_pin, const float* __restrict__ be_pin,
    const float* __restrict__ g_hin, const float* __restrict__ be_hin,
    const float* __restrict__ g_pout, const float* __restrict__ be_pout,
    const float* __restrict__ g_hout, const float* __restrict__ be_hout,
    const float* __restrict__ g_fc, const float* __restrict__ be_fc,
    float* __restrict__ out, int npart) {
  __shared__ float red[4][64];
  __shared__ float buf[4][64];   // a, hd, gate, upd
  const int tid = threadIdx.x, c = tid & 63, q = tid >> 6;
  const int r = blockIdx.x;              // [0,640)
  const int b = r / 80, n = r % 80;
  const int npq = npart >> 2;

  const __half* pp = partial + ((size_t)b * npart + (size_t)q * npq) * 5120 + n * 64 + c;
  float s = 0.f;
  #pragma unroll 8
  for (int jj = 0; jj < npq; ++jj) s += __half2float(pp[(size_t)jj * 5120]);
  red[q][c] = s;
  __syncthreads();

  if (q == 0) {
    const float a_c = red[0][c] + red[1][c] + red[2][c] + red[3][c];
    buf[0][c] = a_c;
    buf[1][c] = head[(size_t)r * 64 + c];

    float pf_in = bpt[c], pf_out = bpt[64 + c];
    float hf_in = bht[c], hf_out = bht[64 + c];
    #pragma unroll 8
    for (int k = 0; k < 64; ++k) {
      const float av = buf[0][k];
      const float hv = buf[1][k];
      pf_in  += av * Wpt[k * 128 + c];
      pf_out += av * Wpt[k * 128 + 64 + c];
      hf_in  += hv * Wht[k * 128 + c];
      hf_out += hv * Wht[k * 128 + 64 + c];
    }
    buf[2][c] = hf_in * pf_in;

    float hg = bhg[c], pg = bpg[c];
    #pragma unroll 8
    for (int k = 0; k < 64; ++k) {
      const float gv = buf[2][k];
      hg += gv * Whg[k * 64 + c];
      pg += gv * Wpg[k * 64 + c];
    }
    const float head_gate = sigmf(lnorm(hg, g_hin, be_hin, c));
    const float pred_gate = sigmf(lnorm(pg, g_pin, be_pin, c));
    const float hfo = lnorm(hf_out, g_hout, be_hout, c);
    const float pfo = lnorm(pf_out, g_pout, be_pout, c);
    buf[3][c] = pred_gate * pfo + head_gate * hfo;

    float fc = bfc[c];
    #pragma unroll 8
    for (int k = 0; k < 64; ++k)
      fc += buf[3][k] * Wfc[k * 64 + c];
    float o = lnorm(fc, g_fc, be_fc, c);
    out[(size_t)r * 64 + c] = fmaxf(o, 0.f);
  }
}

extern "C" void kernel_launch(void* const* d_in, const int* in_sizes, int n_in,
                              void* d_out, int out_size, void* d_ws, size_t ws_size,
                              hipStream_t stream) {
  const float* feat   = (const float*)d_in[0];
  const float* head   = (const float*)d_in[1];
  const float* pred   = (const float*)d_in[2];
  const float* Wpt    = (const float*)d_in[3];
  const float* bpt    = (const float*)d_in[4];
  const float* Wht    = (const float*)d_in[5];
  const float* bht    = (const float*)d_in[6];
  const float* Wpg    = (const float*)d_in[7];
  const float* bpg    = (const float*)d_in[8];
  const float* Whg    = (const float*)d_in[9];
  const float* bhg    = (const float*)d_in[10];
  const float* Wfc    = (const float*)d_in[11];
  const float* bfc    = (const float*)d_in[12];
  const float* g_pin  = (const float*)d_in[13];
  const float* be_pin = (const float*)d_in[14];
  const float* g_hin  = (const float*)d_in[15];
  const float* be_hin = (const float*)d_in[16];
  const float* g_pout = (const float*)d_in[17];
  const float* be_pout= (const float*)d_in[18];
  const float* g_hout = (const float*)d_in[19];
  const float* be_hout= (const float*)d_in[20];
  const float* g_fc   = (const float*)d_in[21];
  const float* be_fc  = (const float*)d_in[22];
  float* out = (float*)d_out;
  __half* partial = (__half*)d_ws;   // 8*128*5120*2 = 10.49 MB (ws proven >= 42 MB)

  hipLaunchKernelGGL(k_assemble_quad, dim3(1024), dim3(256), 0, stream,
                     feat, pred, partial);
  hipLaunchKernelGGL(k_head, dim3(640), dim3(256), 0, stream,
                     partial, head, Wpt, bpt, Wht, bht, Wpg, bpg, Whg, bhg,
                     Wfc, bfc, g_pin, be_pin, g_hin, be_hin, g_pout, be_pout,
                     g_hout, be_hout, g_fc, be_fc, out, 128);
}